// Round 1
// baseline (4489.510 us; speedup 1.0000x reference)
//
#include <hip/hip_runtime.h>
#include <cstdint>
#include <cstddef>

// Problem constants
#define B_   1024
#define T_   200
#define I_   64
#define H_   512
#define HID_ 256
#define LDA_ 1088   // Acat row stride in elements: [h(512) | x_t(64) | c(512)]
#define NG_  2560   // combined step-GEMM N: gates(2048) + d(512)

typedef __bf16 bf16;
typedef __bf16 bf16x8 __attribute__((ext_vector_type(8)));
typedef float  f32x4  __attribute__((ext_vector_type(4)));

__device__ inline void gload_lds16(const bf16* g, void* l) {
  void* gg = (void*)g;  // drop const
  __builtin_amdgcn_global_load_lds((__attribute__((address_space(1))) void*)gg,
                                   (__attribute__((address_space(3))) void*)l,
                                   16, 0, 0);
}

// ---------------------------------------------------------------------------
// bf16 GEMM: C[m][n] = sum_k A[m][k] * W[n][k] + bias[n]
// 128x128 block tile, 4 waves (2x2), 64x64 per wave (4x4 frags of 16x16),
// BK=64, global_load_lds staging with XOR slot-swizzle (slot ^= row&7).
// K-range selected per N-block: n0 < nsplit -> [kb0,ke0), else [kb1,ke1).
// ---------------------------------------------------------------------------
__global__ __launch_bounds__(256)
void gemm_bf16(const bf16* __restrict__ A, int lda,
               const bf16* __restrict__ W, int ldw,
               float* __restrict__ C, int ldc,
               const float* __restrict__ bias,
               int nsplit, int kb0, int ke0, int kb1, int ke1)
{
  __shared__ __align__(16) bf16 As[128 * 64];
  __shared__ __align__(16) bf16 Bs[128 * 64];

  const int tid  = threadIdx.x;
  const int lane = tid & 63;
  const int wave = tid >> 6;
  const int m0 = blockIdx.y * 128;
  const int n0 = blockIdx.x * 128;
  const int kb = (n0 < nsplit) ? kb0 : kb1;
  const int ke = (n0 < nsplit) ? ke0 : ke1;

  // Staging source offsets (in elements). LDS dest is linear; the global
  // source slot is pre-swizzled so that swizzled reads see the right data.
  int aoff[4], boff[4];
#pragma unroll
  for (int r = 0; r < 4; ++r) {
    int o16 = r * 256 + tid;       // 16B-granule index in the 128x64 tile
    int row = o16 >> 3;            // 8 granules per 64-elem row
    int sp  = o16 & 7;             // linear LDS slot
    int s   = sp ^ (row & 7);      // swizzled source slot (involution)
    aoff[r] = row * lda + s * 8;
    boff[r] = row * ldw + s * 8;
  }

  f32x4 acc[4][4];
#pragma unroll
  for (int i = 0; i < 4; ++i)
#pragma unroll
    for (int j = 0; j < 4; ++j) acc[i][j] = (f32x4){0.f, 0.f, 0.f, 0.f};

  const int wm = wave >> 1, wn = wave & 1;
  const int r15 = lane & 15, khalf = lane >> 4, sw = lane & 7;

  for (int kt = kb; kt < ke; kt += 64) {
    const bf16* Ag = A + (size_t)m0 * lda + kt;
    const bf16* Wg = W + (size_t)n0 * ldw + kt;
#pragma unroll
    for (int r = 0; r < 4; ++r) {
      char* la = (char*)As + (size_t)(r * 256 + wave * 64) * 16;
      char* lb = (char*)Bs + (size_t)(r * 256 + wave * 64) * 16;
      gload_lds16(Ag + aoff[r], la);
      gload_lds16(Wg + boff[r], lb);
    }
    __syncthreads();   // compiler emits vmcnt(0) drain before s_barrier

    const bf16x8* Ald = (const bf16x8*)As;
    const bf16x8* Bld = (const bf16x8*)Bs;
#pragma unroll
    for (int kk = 0; kk < 2; ++kk) {
      bf16x8 av[4], bv[4];
#pragma unroll
      for (int i = 0; i < 4; ++i) {
        int ra = wm * 64 + i * 16 + r15;   // A row within tile
        av[i] = Ald[ra * 8 + ((kk * 4 + khalf) ^ sw)];
        int rb = wn * 64 + i * 16 + r15;   // W row (output col) within tile
        bv[i] = Bld[rb * 8 + ((kk * 4 + khalf) ^ sw)];
      }
#pragma unroll
      for (int i = 0; i < 4; ++i)
#pragma unroll
        for (int j = 0; j < 4; ++j)
          acc[i][j] = __builtin_amdgcn_mfma_f32_16x16x32_bf16(av[i], bv[j], acc[i][j], 0, 0, 0);
    }
    __syncthreads();
  }

  // Epilogue: D layout col=lane&15, row=(lane>>4)*4+q (verified m89/m91)
#pragma unroll
  for (int j = 0; j < 4; ++j) {
    int col = n0 + wn * 64 + j * 16 + r15;
    float bb = bias[col];
#pragma unroll
    for (int i = 0; i < 4; ++i) {
      int rbase = m0 + wm * 64 + i * 16 + khalf * 4;
#pragma unroll
      for (int q = 0; q < 4; ++q)
        C[(size_t)(rbase + q) * ldc + col] = acc[i][j][q] + bb;
    }
  }
}

// ---------------------------------------------------------------------------
// Per-step elementwise: consumes G = [gates(2048) | d(512)] (bias included),
// updates fp32 cell state, writes bf16 h/c into Acat, stages x_{t+1}.
// ---------------------------------------------------------------------------
__global__ __launch_bounds__(256)
void ew_step(const float* __restrict__ G, float* __restrict__ c,
             bf16* __restrict__ Acat, const float* __restrict__ x,
             const float* __restrict__ ts, int t)
{
  int idx = blockIdx.x * 256 + threadIdx.x;   // 1024*512 threads
  int b = idx >> 9, j = idx & 511;
  const float* g = G + (size_t)b * NG_;

  float d    = g[2048 + j];
  float cs1  = tanhf(d);
  float cold = c[idx];
  float tt   = ts[(size_t)b * T_ + t];
  float cadj = cold - cs1 + cs1 * tt;

  float fg = 1.f / (1.f + expf(-g[j]));
  float ig = 1.f / (1.f + expf(-g[512 + j]));
  float og = 1.f / (1.f + expf(-g[1024 + j]));
  float cg = 1.f / (1.f + expf(-g[1536 + j]));

  float cn = fg * cadj + ig * cg;
  float hn = og * tanhf(cn);

  c[idx] = cn;
  bf16* arow = Acat + (size_t)b * LDA_;
  arow[j]       = (bf16)hn;
  arow[576 + j] = (bf16)cn;
  if (j < 64 && t + 1 < T_)
    arow[512 + j] = (bf16)x[((size_t)b * T_ + (t + 1)) * I_ + j];
}

// ---------------------------------------------------------------------------
// One-time packing kernels (run inside the graph; cheap)
// ---------------------------------------------------------------------------
__global__ void pack_wcat(const float* __restrict__ Wa, const float* __restrict__ Ua,
                          const float* __restrict__ Wd, bf16* __restrict__ Wc)
{
  int idx = blockIdx.x * 256 + threadIdx.x;   // 2560*1088
  if (idx >= NG_ * LDA_) return;
  int n = idx / LDA_, k = idx - n * LDA_;
  float v = 0.f;
  if (n < 2048) {
    if (k < 512)      v = Wa[(size_t)n * 512 + k];
    else if (k < 576) v = Ua[(size_t)n * 64 + (k - 512)];
  } else {
    if (k >= 576)     v = Wd[(size_t)(n - 2048) * 512 + (k - 576)];
  }
  Wc[idx] = (bf16)v;
}

__global__ void pack_misc(const float* __restrict__ ba, const float* __restrict__ bu,
                          const float* __restrict__ bd, const float* __restrict__ W1,
                          float* __restrict__ bcat, bf16* __restrict__ W1b)
{
  int idx = blockIdx.x * 256 + threadIdx.x;
  if (idx < NG_)
    bcat[idx] = (idx < 2048) ? (ba[idx] + bu[idx]) : bd[idx - 2048];
  if (idx < HID_ * H_)
    W1b[idx] = (bf16)W1[idx];
}

__global__ void init_state(const float* __restrict__ x, bf16* __restrict__ Acat,
                           float* __restrict__ c)
{
  int idx = blockIdx.x * 256 + threadIdx.x;   // covers 1024*1088
  if (idx < B_ * H_) c[idx] = 0.f;
  if (idx >= B_ * LDA_) return;
  int b = idx / LDA_, k = idx - b * LDA_;
  bf16 v = (bf16)0.f;
  if (k >= 512 && k < 576)
    v = (bf16)x[(size_t)b * T_ * I_ + (k - 512)];   // x[:,0,:]
  Acat[idx] = v;
}

// Final: out[b] = b2 + sum_k relu(hidden[b][k]) * W2[k]   (b1 already added)
__global__ void mlp_out(const float* __restrict__ Gm, const float* __restrict__ W2,
                        const float* __restrict__ b2, float* __restrict__ out)
{
  int b = blockIdx.x, l = threadIdx.x;  // 64 threads = 1 wave
  float s = 0.f;
#pragma unroll
  for (int k = l; k < HID_; k += 64)
    s += fmaxf(Gm[(size_t)b * HID_ + k], 0.f) * W2[k];
#pragma unroll
  for (int off = 32; off; off >>= 1) s += __shfl_xor(s, off, 64);
  if (l == 0) out[b] = s + b2[0];
}

// ---------------------------------------------------------------------------
extern "C" void kernel_launch(void* const* d_in, const int* in_sizes, int n_in,
                              void* d_out, int out_size, void* d_ws, size_t ws_size,
                              hipStream_t stream)
{
  const float* x  = (const float*)d_in[0];
  const float* ts = (const float*)d_in[1];
  const float* Wa = (const float*)d_in[2];
  const float* ba = (const float*)d_in[3];
  const float* Ua = (const float*)d_in[4];
  const float* bu = (const float*)d_in[5];
  const float* Wd = (const float*)d_in[6];
  const float* bd = (const float*)d_in[7];
  const float* W1 = (const float*)d_in[8];
  const float* b1 = (const float*)d_in[9];
  const float* W2 = (const float*)d_in[10];
  const float* b2 = (const float*)d_in[11];

  char* ws = (char*)d_ws;
  size_t o = 0;
  auto alloc = [&](size_t bytes) {
    size_t p = o;
    o += (bytes + 255) & ~(size_t)255;
    return p;
  };
  bf16*  Wcat = (bf16*) (ws + alloc((size_t)NG_ * LDA_ * 2));   // 5.57 MB
  float* bcat = (float*)(ws + alloc((size_t)NG_ * 4));
  bf16*  W1b  = (bf16*) (ws + alloc((size_t)HID_ * H_ * 2));
  bf16*  Acat = (bf16*) (ws + alloc((size_t)B_ * LDA_ * 2));    // 2.23 MB
  float* cbuf = (float*)(ws + alloc((size_t)B_ * H_ * 4));      // 2.10 MB
  float* G    = (float*)(ws + alloc((size_t)B_ * NG_ * 4));     // 10.49 MB

  pack_wcat<<<(NG_ * LDA_ + 255) / 256, 256, 0, stream>>>(Wa, Ua, Wd, Wcat);
  pack_misc<<<(HID_ * H_ + 255) / 256, 256, 0, stream>>>(ba, bu, bd, W1, bcat, W1b);
  init_state<<<(B_ * LDA_ + 255) / 256, 256, 0, stream>>>(x, Acat, cbuf);

  for (int t = 0; t < T_; ++t) {
    // combined GEMM: cols 0..2047 = gates (K=0..576), cols 2048..2559 = d (K=576..1088)
    gemm_bf16<<<dim3(NG_ / 128, B_ / 128), 256, 0, stream>>>(
        Acat, LDA_, Wcat, LDA_, G, NG_, bcat, 2048, 0, 576, 576, 1088);
    ew_step<<<(B_ * H_) / 256, 256, 0, stream>>>(G, cbuf, Acat, x, ts, t);
  }

  // MLP head: hidden = relu(h @ W1^T + b1) via same GEMM (A = h part of Acat)
  gemm_bf16<<<dim3(HID_ / 128, B_ / 128), 256, 0, stream>>>(
      Acat, LDA_, W1b, H_, G, HID_, b1, 1 << 30, 0, 512, 0, 512);
  mlp_out<<<B_, 64, 0, stream>>>(G, W2, b2, (float*)d_out);
}